// Round 9
// baseline (285.059 us; speedup 1.0000x reference)
//
#include <hip/hip_runtime.h>
#include <hip/hip_bf16.h>

// MultiAgentSEPSNetwork: A=8 agents, E=4096, O=256, H1=H2=1024, H3=512, S=4.
// M = A*E = 32768 rows. Only the seps_idx-selected net per agent is computed.
//
// R9 vs R8 (L2 GEMM 88us, MfmaUtil 34.5%, Occ 19% = 8 waves/CU, LDS-capped
// at 2 blocks by the 64KB BK=64 dbuf; LDS pipe ~62% busy, HBM 24% -> neither
// saturated; slack = too little TLP):
//  - BK=32 double buffer -> 32KB LDS -> 3 blocks/CU (register-capped at
//    152 VGPR x 3 waves/SIMD). Barrier-drain coverage shrinks to ~256cyc of
//    MFMA, but post-swizzle A/B staging is L2-hot (~200-300cyc) and 3
//    interleaved blocks hide the residual.
//  - __launch_bounds__(256,3) pins regalloc at 3 waves/EU.
// Kept: R3 XOR-swizzled BK=32 LDS layout (0 conflicts, coalesced DMA),
// R8 XCD grid swizzle (FETCH 240->98MB), fused prep, coalesced epilogue.

typedef unsigned short u16;
typedef __bf16 bf16x8 __attribute__((ext_vector_type(8)));
typedef float floatx4 __attribute__((ext_vector_type(4)));
typedef unsigned short ushort8 __attribute__((ext_vector_type(8)));

__device__ __forceinline__ u16 f2bf(float f) {
    union { float f; unsigned int u; } v; v.f = f;
    unsigned int u = v.u;
    return (u16)((u + 0x7FFFu + ((u >> 16) & 1u)) >> 16);
}

// global -> LDS direct DMA, 16 B/lane. LDS dest = wave-uniform base + lane*16.
__device__ __forceinline__ void load16(const void* g, void* l) {
    __builtin_amdgcn_global_load_lds(
        (const __attribute__((address_space(1))) void*)(unsigned long long)g,
        (__attribute__((address_space(3))) void*)(unsigned int)(unsigned long long)l,
        16, 0, 0);
}

// ---------------- fused prep: x->bf16 + 3 weight transposes ----------------
__global__ __launch_bounds__(256) void prep(
    const float* __restrict__ x, u16* __restrict__ xb,
    const float* __restrict__ W1, u16* __restrict__ w1t,
    const float* __restrict__ W2, u16* __restrict__ w2t,
    const float* __restrict__ W3, u16* __restrict__ w3t) {
    __shared__ float tile[32][33];
    int b = blockIdx.x;
    const int tid = threadIdx.x;
    if (b < 8192) {
        int i = (b * 256 + tid) * 4;
        float4 v = *(const float4*)(x + i);
        ushort4 o;
        o.x = f2bf(v.x); o.y = f2bf(v.y); o.z = f2bf(v.z); o.w = f2bf(v.w);
        *(ushort4*)(xb + i) = o;
        return;
    }
    b -= 8192;
    const float* src; u16* dst; int K, N, n0, k0, s;
    if (b < 1024) {                     // W1 [4][256][1024] -> [4][1024][256]
        s = b >> 8; int r = b & 255;
        K = 256; N = 1024; n0 = (r & 31) * 32; k0 = (r >> 5) * 32;
        src = W1; dst = w1t;
    } else if (b < 5120) {              // W2 [4][1024][1024] -> same^T
        b -= 1024; s = b >> 10; int r = b & 1023;
        K = 1024; N = 1024; n0 = (r & 31) * 32; k0 = (r >> 5) * 32;
        src = W2; dst = w2t;
    } else {                            // W3 [4][1024][512] -> [4][512][1024]
        b -= 5120; s = b >> 9; int r = b & 511;
        K = 1024; N = 512; n0 = (r & 15) * 32; k0 = (r >> 4) * 32;
        src = W3; dst = w3t;
    }
    src += (size_t)s * K * N;
    dst += (size_t)s * N * K;
    const int tx = tid & 31, ty = tid >> 5;
#pragma unroll
    for (int j = 0; j < 32; j += 8)
        tile[ty + j][tx] = src[(size_t)(k0 + ty + j) * N + (n0 + tx)];
    __syncthreads();
#pragma unroll
    for (int j = 0; j < 32; j += 8)
        dst[(size_t)(n0 + ty + j) * K + (k0 + tx)] = f2bf(tile[tx][ty + j]);
}

// ------- grouped GEMM: BK=32 dbuf K-loop + XCD-swizzled grid -------
// C[m,n] = act(A[M,K] @ Wt[s][N,K]^T + bias[s][N]);  s = seps[agent(m)]
// 128x128 tile, BK=32 x2 buffers (32KB), 256 thr = 4 waves (2x2),
// 64x64/wave, 16x16x32 MFMA, 3 blocks/CU.
template <int K, int N, bool RELU, bool OUT_BF16>
__global__ __launch_bounds__(256, 3) void gemm_mlp(
    const u16* __restrict__ Amat, const u16* __restrict__ Wt,
    const float* __restrict__ bias, const int* __restrict__ seps,
    void* __restrict__ outp) {
    constexpr int BM = 128, BN = 128, BK = 32;
    constexpr int NIT = K / BK;
    constexpr int NNB = N / 128;               // n-blocks per m-stripe (8 or 4)
    constexpr int LNB = (NNB == 8) ? 3 : 2;
    constexpr int EW = 132;                    // epilogue f32 row stride
    __shared__ u16 lds[2 * 8192];              // 32 KB: buf b at b*8192; A, then B at +4096
    float* eps = (float*)lds;                  // 32x132 f32 = 16.9KB (epilogue reuse)

    const int tid = threadIdx.x;
    const int wave = tid >> 6, lane = tid & 63;
    const int wm = wave >> 1, wn = wave & 1;
    const int quad = lane >> 4, l16 = lane & 15;

    // XCD swizzle: block i -> XCD i%8; all NNB n-blocks of one m-stripe are
    // dispatch-adjacent and share i%8 == mb%8 -> A-stripe lives in one L2.
    const int bidx = blockIdx.x;
    const int t = bidx >> 3;
    const int mb = (t >> LNB) * 8 + (bidx & 7);
    const int nb = t & (NNB - 1);
    const int m0 = mb * BM;
    const int n0 = nb * BN;

    const int s = seps[m0 >> 12];              // 4096 rows per agent
    const u16* Ab = Amat + (size_t)m0 * K;
    const u16* Bb = Wt + ((size_t)s * N + n0) * K;

    // staging (R3 scheme): chunk = 16 rows x 32k (1KB); lane L -> row
    // c*16+(L>>2), k-chunk (L&3)^((L>>3)&3) -> same contiguous 64B global
    // row segment per 4 lanes (coalesced), XOR slot swizzle in LDS.
    const int srow0 = lane >> 2;
    const int scol = (((lane & 3) ^ ((lane >> 3) & 3)) * 8);

    floatx4 acc[4][4];
#pragma unroll
    for (int i = 0; i < 4; ++i)
#pragma unroll
        for (int j = 0; j < 4; ++j) acc[i][j] = (floatx4){0.f, 0.f, 0.f, 0.f};

    // prologue: stage tile 0 into buf 0 (A chunks 0..7 at 0, B at +4096)
#pragma unroll
    for (int j = 0; j < 2; ++j) {
        const int c = wave * 2 + j;
        const int row = c * 16 + srow0;
        load16(Ab + (size_t)row * K + scol, &lds[c * 512]);
        load16(Bb + (size_t)row * K + scol, &lds[4096 + c * 512]);
    }

    for (int it = 0; it < NIT; ++it) {
        __syncthreads();   // drains loads into buf it&1 (issued during prev compute)
        if (it + 1 < NIT) {
            const int k0 = (it + 1) * BK;
            u16* dstb = &lds[((it + 1) & 1) * 8192];
#pragma unroll
            for (int j = 0; j < 2; ++j) {
                const int c = wave * 2 + j;
                const int row = c * 16 + srow0;
                load16(Ab + (size_t)row * K + k0 + scol, dstb + c * 512);
                load16(Bb + (size_t)row * K + k0 + scol, dstb + 4096 + c * 512);
            }
        }
        const u16* smA = &lds[(it & 1) * 8192];
        const u16* smB = smA + 4096;
        const int slot = (quad ^ ((l16 >> 1) & 3)) * 8;
        bf16x8 af[4], bfv[4];
#pragma unroll
        for (int t2 = 0; t2 < 4; ++t2) {
            af[t2]  = *(const bf16x8*)&smA[(wm * 4 + t2) * 512 + l16 * 32 + slot];
            bfv[t2] = *(const bf16x8*)&smB[(wn * 4 + t2) * 512 + l16 * 32 + slot];
        }
#pragma unroll
        for (int mt = 0; mt < 4; ++mt)
#pragma unroll
            for (int nt = 0; nt < 4; ++nt)
                acc[mt][nt] = __builtin_amdgcn_mfma_f32_16x16x32_bf16(
                    af[mt], bfv[nt], acc[mt][nt], 0, 0, 0);
    }
    __syncthreads();   // all waves done with LDS tiles before epilogue reuse

    // ---- epilogue: 4 phases, LDS transpose, 16B/lane coalesced stores ----
    float bv[4];
#pragma unroll
    for (int nt = 0; nt < 4; ++nt)
        bv[nt] = bias[s * N + n0 + wn * 64 + nt * 16 + l16];

    const int rr = tid >> 4;      // 0..15
    const int cg = tid & 15;      // 0..15 (8 cols each)

#pragma unroll
    for (int mt = 0; mt < 4; ++mt) {
#pragma unroll
        for (int nt = 0; nt < 4; ++nt) {
#pragma unroll
            for (int r2 = 0; r2 < 4; ++r2) {
                float v = acc[mt][nt][r2] + bv[nt];
                if (RELU) v = fmaxf(v, 0.0f);
                eps[(wm * 16 + quad * 4 + r2) * EW + wn * 64 + nt * 16 + l16] = v;
            }
        }
        __syncthreads();
#pragma unroll
        for (int p = 0; p < 2; ++p) {
            const int lrow = p * 16 + rr;  // 0..31
            const int grow = m0 + ((lrow < 16) ? (mt * 16 + lrow)
                                               : (64 + mt * 16 + (lrow - 16)));
            const float* src = eps + lrow * EW + cg * 8;
            float4 v0 = *(const float4*)(src);
            float4 v1 = *(const float4*)(src + 4);
            if (OUT_BF16) {
                ushort8 o;
                o[0] = f2bf(v0.x); o[1] = f2bf(v0.y); o[2] = f2bf(v0.z); o[3] = f2bf(v0.w);
                o[4] = f2bf(v1.x); o[5] = f2bf(v1.y); o[6] = f2bf(v1.z); o[7] = f2bf(v1.w);
                *(ushort8*)((u16*)outp + (size_t)grow * N + n0 + cg * 8) = o;
            } else {
                float* dst = (float*)outp + (size_t)grow * N + n0 + cg * 8;
                *(float4*)dst = v0;
                *(float4*)(dst + 4) = v1;
            }
        }
        __syncthreads();
    }
}

extern "C" void kernel_launch(void* const* d_in, const int* in_sizes, int n_in,
                              void* d_out, int out_size, void* d_ws, size_t ws_size,
                              hipStream_t stream) {
    const float* x  = (const float*)d_in[0];
    const float* W1 = (const float*)d_in[1];
    const float* b1 = (const float*)d_in[2];
    const float* W2 = (const float*)d_in[3];
    const float* b2 = (const float*)d_in[4];
    const float* W3 = (const float*)d_in[5];
    const float* b3 = (const float*)d_in[6];
    const int* seps = (const int*)d_in[7];

    char* ws = (char*)d_ws;
    u16* w1t = (u16*)(ws);                    //  2 MB: [4][1024][256]
    u16* w2t = (u16*)(ws + (2ull << 20));     //  8 MB: [4][1024][1024]
    u16* w3t = (u16*)(ws + (10ull << 20));    //  4 MB: [4][512][1024]
    u16* xb  = (u16*)(ws + (14ull << 20));    // 16 MB: [32768][256]
    u16* h1  = (u16*)(ws + (30ull << 20));    // 64 MB: [32768][1024]
    u16* h2  = (u16*)(ws + (94ull << 20));    // 64 MB: [32768][1024]

    prep<<<15360, 256, 0, stream>>>(x, xb, W1, w1t, W2, w2t, W3, w3t);

    // L1: [32768,256]@[256,1024]^T +b1, relu -> h1 (bf16)
    gemm_mlp<256, 1024, true, true><<<2048, 256, 0, stream>>>(xb, w1t, b1, seps, h1);
    // L2: [32768,1024]@[1024,1024]^T +b2, relu -> h2 (bf16)
    gemm_mlp<1024, 1024, true, true><<<2048, 256, 0, stream>>>(h1, w2t, b2, seps, h2);
    // L3: [32768,1024]@[1024,512]^T +b3 -> out (f32)
    gemm_mlp<1024, 512, false, false><<<1024, 256, 0, stream>>>(h2, w3t, b3, seps, d_out);
}